// Round 1
// baseline (974.938 us; speedup 1.0000x reference)
//
#include <hip/hip_runtime.h>
#include <hip/hip_bf16.h>

typedef __bf16 bf16x8 __attribute__((ext_vector_type(8)));
typedef float f32x4 __attribute__((ext_vector_type(4)));

__device__ __forceinline__ float bf2f(unsigned int u) {
    unsigned int x = u << 16;
    return __builtin_bit_cast(float, x);
}
__device__ __forceinline__ unsigned short f2bf(float f) {
    unsigned int x = __builtin_bit_cast(unsigned int, f);
    x += 0x7fffu + ((x >> 16) & 1u);   // RNE
    return (unsigned short)(x >> 16);
}

__device__ __forceinline__ void gld_lds16(const unsigned short* g, unsigned short* s) {
    __builtin_amdgcn_global_load_lds((const __attribute__((address_space(1))) void*)g,
                                     (__attribute__((address_space(3))) void*)s, 16, 0, 0);
}

// C[m,n] = sum_k A[m,k]*B[n,k] + bias[n].  A row stride = lda, B row stride = K.
// 128x128 tile, BK=32, 4 waves in 2x2, 16x16x32 bf16 MFMA (m97 structure).
template<bool OUT_F32>
__global__ __launch_bounds__(256) void gemm_bt(
    const unsigned short* __restrict__ A, int lda,
    const unsigned short* __restrict__ B,
    const float* __restrict__ bias,
    void* __restrict__ C, int N, int K)
{
    __shared__ unsigned short As[128 * 32];
    __shared__ unsigned short Bs[128 * 32];
    const int tid   = threadIdx.x;
    const int lane  = tid & 63;
    const int wave  = tid >> 6;
    const int wm    = (wave >> 1) * 64;
    const int wn    = (wave & 1) * 64;
    const int lrow  = lane & 15;
    const int lquad = lane >> 4;
    const long bm = (long)blockIdx.y * 128;
    const long bn = (long)blockIdx.x * 128;

    f32x4 acc[4][4];
#pragma unroll
    for (int i = 0; i < 4; i++)
#pragma unroll
        for (int j = 0; j < 4; j++)
            acc[i][j] = (f32x4){0.f, 0.f, 0.f, 0.f};

    // staging: 128x32 bf16 tile = 512 chunks of 16B; thread t does chunks t and t+256.
    const int r0 = tid >> 2;
    const int c0 = (tid & 3) * 8;
    const unsigned short* Ag0 = A + (bm + r0) * (long)lda + c0;
    const unsigned short* Ag1 = A + (bm + r0 + 64) * (long)lda + c0;
    const unsigned short* Bg0 = B + (bn + r0) * (long)K + c0;
    const unsigned short* Bg1 = B + (bn + r0 + 64) * (long)K + c0;
    unsigned short* As0 = &As[tid * 8];
    unsigned short* As1 = &As[tid * 8 + 2048];
    unsigned short* Bs0 = &Bs[tid * 8];
    unsigned short* Bs1 = &Bs[tid * 8 + 2048];

    for (int k0 = 0; k0 < K; k0 += 32) {
        gld_lds16(Ag0 + k0, As0);
        gld_lds16(Ag1 + k0, As1);
        gld_lds16(Bg0 + k0, Bs0);
        gld_lds16(Bg1 + k0, Bs1);
        __syncthreads();
        bf16x8 af[4], bq[4];
#pragma unroll
        for (int i = 0; i < 4; i++)
            af[i] = *(const bf16x8*)&As[(wm + i * 16 + lrow) * 32 + lquad * 8];
#pragma unroll
        for (int j = 0; j < 4; j++)
            bq[j] = *(const bf16x8*)&Bs[(wn + j * 16 + lrow) * 32 + lquad * 8];
#pragma unroll
        for (int i = 0; i < 4; i++)
#pragma unroll
            for (int j = 0; j < 4; j++)
                acc[i][j] = __builtin_amdgcn_mfma_f32_16x16x32_bf16(af[i], bq[j], acc[i][j], 0, 0, 0);
        __syncthreads();
    }

    // epilogue: C/D layout col=lane&15, row=quad*4+reg
#pragma unroll
    for (int j = 0; j < 4; j++) {
        const int col = (int)bn + wn + j * 16 + lrow;
        const float bvv = bias[col];
#pragma unroll
        for (int i = 0; i < 4; i++) {
            const long rowb = bm + wm + i * 16 + lquad * 4;
#pragma unroll
            for (int r = 0; r < 4; r++) {
                float v = acc[i][j][r] + bvv;
                if (OUT_F32)
                    ((float*)C)[(rowb + r) * (long)N + col] = v;
                else
                    ((unsigned short*)C)[(rowb + r) * (long)N + col] = f2bf(v);
            }
        }
    }
}

// Per (group,head): 4x4 scores over hd=128, diagonal masked, softmax, o = A@v.
// One wave per (group,head); each lane owns 2 dims.
__global__ __launch_bounds__(256) void attn4(
    const unsigned short* __restrict__ QK,  // [M][2048]: q cols 0..1023, k cols 1024..2047
    const unsigned short* __restrict__ V,   // [M][1024]
    unsigned short* __restrict__ O)         // [M][1024]
{
    const int wave = threadIdx.x >> 6;
    const int lane = threadIdx.x & 63;
    const int gh = blockIdx.x * 4 + wave;   // 0..65535
    const int g = gh >> 3, h = gh & 7;
    const long row0 = (long)g * 4;
    const int dof = h * 128 + lane * 2;
    const float scale = 0.08838834764831845f;  // 1/sqrt(128)

    float q[4][2], k[4][2], v[4][2];
#pragma unroll
    for (int i = 0; i < 4; i++) {
        const unsigned short* qr = QK + (row0 + i) * 2048 + dof;
        unsigned int uq = *(const unsigned int*)qr;
        unsigned int uk = *(const unsigned int*)(qr + 1024);
        unsigned int uv = *(const unsigned int*)(V + (row0 + i) * 1024 + dof);
        q[i][0] = bf2f(uq & 0xffffu); q[i][1] = bf2f(uq >> 16);
        k[i][0] = bf2f(uk & 0xffffu); k[i][1] = bf2f(uk >> 16);
        v[i][0] = bf2f(uv & 0xffffu); v[i][1] = bf2f(uv >> 16);
    }
    float s[4][4];
#pragma unroll
    for (int i = 0; i < 4; i++)
#pragma unroll
        for (int j = 0; j < 4; j++)
            s[i][j] = q[i][0] * k[j][0] + q[i][1] * k[j][1];
#pragma unroll
    for (int m = 1; m < 64; m <<= 1)
#pragma unroll
        for (int i = 0; i < 4; i++)
#pragma unroll
            for (int j = 0; j < 4; j++)
                s[i][j] += __shfl_xor(s[i][j], m, 64);

#pragma unroll
    for (int i = 0; i < 4; i++) {
        float mx = -3.0e38f;
#pragma unroll
        for (int j = 0; j < 4; j++)
            if (j != i) mx = fmaxf(mx, s[i][j] * scale);
        float p[4], den = 0.f;
#pragma unroll
        for (int j = 0; j < 4; j++) {
            p[j] = (j == i) ? 0.f : __expf(s[i][j] * scale - mx);
            den += p[j];
        }
        const float inv = 1.f / den;
        float o0 = 0.f, o1 = 0.f;
#pragma unroll
        for (int j = 0; j < 4; j++) {
            const float a = p[j] * inv;
            o0 += a * v[j][0];
            o1 += a * v[j][1];
        }
        unsigned int packed = (unsigned int)f2bf(o0) | ((unsigned int)f2bf(o1) << 16);
        *(unsigned int*)(O + (row0 + i) * 1024 + dof) = packed;
    }
}

__global__ __launch_bounds__(256) void cvt_bf16(const float* __restrict__ in,
                                                unsigned short* __restrict__ out, int n4)
{
    int i = blockIdx.x * blockDim.x + threadIdx.x;
    if (i >= n4) return;
    float4 v = ((const float4*)in)[i];
    unsigned int a = (unsigned int)f2bf(v.x) | ((unsigned int)f2bf(v.y) << 16);
    unsigned int b = (unsigned int)f2bf(v.z) | ((unsigned int)f2bf(v.w) << 16);
    ((uint2*)out)[i] = make_uint2(a, b);
}

extern "C" void kernel_launch(void* const* d_in, const int* in_sizes, int n_in,
                              void* d_out, int out_size, void* d_ws, size_t ws_size,
                              hipStream_t stream)
{
    (void)in_sizes; (void)n_in; (void)out_size; (void)ws_size;
    const float* x    = (const float*)d_in[0];
    const float* wqk  = (const float*)d_in[1];
    const float* bqk  = (const float*)d_in[2];
    const float* wv   = (const float*)d_in[3];
    const float* bv   = (const float*)d_in[4];
    const float* win  = (const float*)d_in[5];
    const float* bin  = (const float*)d_in[6];
    const float* wout = (const float*)d_in[7];
    const float* bout = (const float*)d_in[8];

    // M = B*S = 32768 rows; pad segment's output is sliced off -> skip it entirely.
    char* ws = (char*)d_ws;
    unsigned short* buf0 = (unsigned short*)ws;                    // 64MB: x16, later v
    unsigned short* y1   = (unsigned short*)(ws + (64ll << 20));   // 128MB: [qk_in|v_in], later o
    unsigned short* qkb  = (unsigned short*)(ws + (192ll << 20));  // 128MB: [q|k]
    unsigned short* wcat = (unsigned short*)(ws + (320ll << 20));  // 4MB  [Wqk;Wv] bf16
    unsigned short* wqkv = (unsigned short*)(ws + (324ll << 20));  // 6MB  in_proj_w bf16
    unsigned short* wo16 = (unsigned short*)(ws + (330ll << 20));  // 2MB  out_proj_w bf16
    float*          bcat = (float*)(ws + (332ll << 20));           // 8KB  [bqk;bv]
    unsigned short* o16  = y1;                                     // reuse after stage2

    cvt_bf16<<<32768, 256, 0, stream>>>(x, buf0, 33554432 / 4);
    cvt_bf16<<<1024, 256, 0, stream>>>(wqk, wcat, 262144);
    cvt_bf16<<<1024, 256, 0, stream>>>(wv, wcat + 1048576, 262144);
    cvt_bf16<<<3072, 256, 0, stream>>>(win, wqkv, 786432);
    cvt_bf16<<<1024, 256, 0, stream>>>(wout, wo16, 262144);
    hipMemcpyAsync(bcat, bqk, 1024 * sizeof(float), hipMemcpyDeviceToDevice, stream);
    hipMemcpyAsync(bcat + 1024, bv, 1024 * sizeof(float), hipMemcpyDeviceToDevice, stream);

    dim3 blk(256);
    // stage1: y1[M,2048] = x16 @ [Wqk;Wv]^T + [bqk;bv]
    gemm_bt<false><<<dim3(16, 256), blk, 0, stream>>>(buf0, 1024, wcat, bcat, y1, 2048, 1024);
    // stage2a: qkb[M,2048] = qk_in @ [Wq;Wk]^T + b  (qk_in = y1 cols 0..1023, lda=2048)
    gemm_bt<false><<<dim3(16, 256), blk, 0, stream>>>(y1, 2048, wqkv, bin, qkb, 2048, 1024);
    // stage2b: v[M,1024] = v_in @ Wv2^T + b  (v_in = y1 cols 1024..2047)
    gemm_bt<false><<<dim3(8, 256), blk, 0, stream>>>(y1 + 1024, 2048, wqkv + 2048 * 1024,
                                                     bin + 2048, buf0, 1024, 1024);
    // stage3: attention within 4-token groups
    attn4<<<16384, blk, 0, stream>>>(qkb, buf0, o16);
    // stage4: out[M,1024] fp32 = o @ Wo^T + bo
    gemm_bt<true><<<dim3(8, 256), blk, 0, stream>>>(o16, 1024, wo16, bout, d_out, 1024, 1024);
}

// Round 2
// 743.771 us; speedup vs baseline: 1.3108x; 1.3108x over previous
//
#include <hip/hip_runtime.h>
#include <hip/hip_bf16.h>

typedef __bf16 bf16x8 __attribute__((ext_vector_type(8)));
typedef float f32x4 __attribute__((ext_vector_type(4)));

__device__ __forceinline__ float bf2f(unsigned int u) {
    unsigned int x = u << 16;
    return __builtin_bit_cast(float, x);
}
__device__ __forceinline__ unsigned short f2bf(float f) {
    unsigned int x = __builtin_bit_cast(unsigned int, f);
    x += 0x7fffu + ((x >> 16) & 1u);   // RNE
    return (unsigned short)(x >> 16);
}

__device__ __forceinline__ void gld_lds16(const unsigned short* g, unsigned short* s) {
    __builtin_amdgcn_global_load_lds((const __attribute__((address_space(1))) void*)g,
                                     (__attribute__((address_space(3))) void*)s, 16, 0, 0);
}

// C[m,n] = sum_k A[m,k]*B[n,k] + bias[n].  A row stride = lda, B row stride = K.
// 128x128 tile, BK=32, 4 waves in 2x2, 16x16x32 bf16 MFMA (m97 structure).
// bias may be nullptr (treated as 0).
template<bool OUT_F32>
__global__ __launch_bounds__(256) void gemm_bt(
    const unsigned short* __restrict__ A, int lda,
    const unsigned short* __restrict__ B,
    const float* __restrict__ bias,
    void* __restrict__ C, int N, int K)
{
    __shared__ unsigned short As[128 * 32];
    __shared__ unsigned short Bs[128 * 32];
    const int tid   = threadIdx.x;
    const int lane  = tid & 63;
    const int wave  = tid >> 6;
    const int wm    = (wave >> 1) * 64;
    const int wn    = (wave & 1) * 64;
    const int lrow  = lane & 15;
    const int lquad = lane >> 4;
    const long bm = (long)blockIdx.y * 128;
    const long bn = (long)blockIdx.x * 128;

    f32x4 acc[4][4];
#pragma unroll
    for (int i = 0; i < 4; i++)
#pragma unroll
        for (int j = 0; j < 4; j++)
            acc[i][j] = (f32x4){0.f, 0.f, 0.f, 0.f};

    const int r0 = tid >> 2;
    const int c0 = (tid & 3) * 8;
    const unsigned short* Ag0 = A + (bm + r0) * (long)lda + c0;
    const unsigned short* Ag1 = A + (bm + r0 + 64) * (long)lda + c0;
    const unsigned short* Bg0 = B + (bn + r0) * (long)K + c0;
    const unsigned short* Bg1 = B + (bn + r0 + 64) * (long)K + c0;
    unsigned short* As0 = &As[tid * 8];
    unsigned short* As1 = &As[tid * 8 + 2048];
    unsigned short* Bs0 = &Bs[tid * 8];
    unsigned short* Bs1 = &Bs[tid * 8 + 2048];

    for (int k0 = 0; k0 < K; k0 += 32) {
        gld_lds16(Ag0 + k0, As0);
        gld_lds16(Ag1 + k0, As1);
        gld_lds16(Bg0 + k0, Bs0);
        gld_lds16(Bg1 + k0, Bs1);
        __syncthreads();
        bf16x8 af[4], bq[4];
#pragma unroll
        for (int i = 0; i < 4; i++)
            af[i] = *(const bf16x8*)&As[(wm + i * 16 + lrow) * 32 + lquad * 8];
#pragma unroll
        for (int j = 0; j < 4; j++)
            bq[j] = *(const bf16x8*)&Bs[(wn + j * 16 + lrow) * 32 + lquad * 8];
#pragma unroll
        for (int i = 0; i < 4; i++)
#pragma unroll
            for (int j = 0; j < 4; j++)
                acc[i][j] = __builtin_amdgcn_mfma_f32_16x16x32_bf16(af[i], bq[j], acc[i][j], 0, 0, 0);
        __syncthreads();
    }

    // epilogue: C/D layout col=lane&15, row=quad*4+reg
#pragma unroll
    for (int j = 0; j < 4; j++) {
        const int col = (int)bn + wn + j * 16 + lrow;
        const float bvv = bias ? bias[col] : 0.f;
#pragma unroll
        for (int i = 0; i < 4; i++) {
            const long rowb = bm + wm + i * 16 + lquad * 4;
#pragma unroll
            for (int r = 0; r < 4; r++) {
                float v = acc[i][j][r] + bvv;
                if (OUT_F32)
                    ((float*)C)[(rowb + r) * (long)N + col] = v;
                else
                    ((unsigned short*)C)[(rowb + r) * (long)N + col] = f2bf(v);
            }
        }
    }
}

// Per (group,head): 4x4 scores over hd=128, diagonal masked, softmax, o = A@v.
// QKV layout [M][3072]: q cols 0..1023, k 1024..2047, v 2048..3071.
__global__ __launch_bounds__(256) void attn4(
    const unsigned short* __restrict__ QKV,
    unsigned short* __restrict__ O)         // [M][1024]
{
    const int wave = threadIdx.x >> 6;
    const int lane = threadIdx.x & 63;
    const int gh = blockIdx.x * 4 + wave;   // 0..65535
    const int g = gh >> 3, h = gh & 7;
    const long row0 = (long)g * 4;
    const int dof = h * 128 + lane * 2;
    const float scale = 0.08838834764831845f;  // 1/sqrt(128)

    float q[4][2], k[4][2], v[4][2];
#pragma unroll
    for (int i = 0; i < 4; i++) {
        const unsigned short* qr = QKV + (row0 + i) * 3072 + dof;
        unsigned int uq = *(const unsigned int*)qr;
        unsigned int uk = *(const unsigned int*)(qr + 1024);
        unsigned int uv = *(const unsigned int*)(qr + 2048);
        q[i][0] = bf2f(uq & 0xffffu); q[i][1] = bf2f(uq >> 16);
        k[i][0] = bf2f(uk & 0xffffu); k[i][1] = bf2f(uk >> 16);
        v[i][0] = bf2f(uv & 0xffffu); v[i][1] = bf2f(uv >> 16);
    }
    float s[4][4];
#pragma unroll
    for (int i = 0; i < 4; i++)
#pragma unroll
        for (int j = 0; j < 4; j++)
            s[i][j] = q[i][0] * k[j][0] + q[i][1] * k[j][1];
#pragma unroll
    for (int m = 1; m < 64; m <<= 1)
#pragma unroll
        for (int i = 0; i < 4; i++)
#pragma unroll
            for (int j = 0; j < 4; j++)
                s[i][j] += __shfl_xor(s[i][j], m, 64);

#pragma unroll
    for (int i = 0; i < 4; i++) {
        float mx = -3.0e38f;
#pragma unroll
        for (int j = 0; j < 4; j++)
            if (j != i) mx = fmaxf(mx, s[i][j] * scale);
        float p[4], den = 0.f;
#pragma unroll
        for (int j = 0; j < 4; j++) {
            p[j] = (j == i) ? 0.f : __expf(s[i][j] * scale - mx);
            den += p[j];
        }
        const float inv = 1.f / den;
        float o0 = 0.f, o1 = 0.f;
#pragma unroll
        for (int j = 0; j < 4; j++) {
            const float a = p[j] * inv;
            o0 += a * v[j][0];
            o1 += a * v[j][1];
        }
        unsigned int packed = (unsigned int)f2bf(o0) | ((unsigned int)f2bf(o1) << 16);
        *(unsigned int*)(O + (row0 + i) * 1024 + dof) = packed;
    }
}

__global__ __launch_bounds__(256) void cvt_bf16(const float* __restrict__ in,
                                                unsigned short* __restrict__ out, int n4)
{
    int i = blockIdx.x * blockDim.x + threadIdx.x;
    if (i >= n4) return;
    float4 v = ((const float4*)in)[i];
    unsigned int a = (unsigned int)f2bf(v.x) | ((unsigned int)f2bf(v.y) << 16);
    unsigned int b = (unsigned int)f2bf(v.z) | ((unsigned int)f2bf(v.w) << 16);
    ((uint2*)out)[i] = make_uint2(a, b);
}

// out[j][i] = bf16(in[i][j]) for n x n fp32 in.
__global__ __launch_bounds__(256) void transpose_cvt(const float* __restrict__ in,
                                                     unsigned short* __restrict__ out, int n)
{
    __shared__ unsigned short tile[64][65];
    const int bx = blockIdx.x * 64, by = blockIdx.y * 64;
    const int tx = threadIdx.x & 63, ty = threadIdx.x >> 6;
    for (int r = ty; r < 64; r += 4)
        tile[r][tx] = f2bf(in[(long)(by + r) * n + bx + tx]);
    __syncthreads();
    for (int r = ty; r < 64; r += 4)
        out[(long)(bx + r) * n + by + tx] = tile[tx][r];
}

// bbig[row] = dot(win[row,:], row<2048 ? bqk : bv) + bin[row]; fp32 exact path.
__global__ __launch_bounds__(256) void bias_prep(const float* __restrict__ win,
                                                 const float* __restrict__ bqk,
                                                 const float* __restrict__ bv,
                                                 const float* __restrict__ bin,
                                                 float* __restrict__ bbig)
{
    const int row = blockIdx.x * 4 + (threadIdx.x >> 6);
    const int lane = threadIdx.x & 63;
    const float* b = (row < 2048) ? bqk : bv;
    float s = 0.f;
    for (int t = lane; t < 1024; t += 64) s += win[(long)row * 1024 + t] * b[t];
#pragma unroll
    for (int m = 1; m < 64; m <<= 1) s += __shfl_xor(s, m, 64);
    if (lane == 0) bbig[row] = s + bin[row];
}

extern "C" void kernel_launch(void* const* d_in, const int* in_sizes, int n_in,
                              void* d_out, int out_size, void* d_ws, size_t ws_size,
                              hipStream_t stream)
{
    (void)in_sizes; (void)n_in; (void)out_size; (void)ws_size;
    const float* x    = (const float*)d_in[0];
    const float* wqk  = (const float*)d_in[1];
    const float* bqk  = (const float*)d_in[2];
    const float* wv   = (const float*)d_in[3];
    const float* bv   = (const float*)d_in[4];
    const float* win  = (const float*)d_in[5];
    const float* bin  = (const float*)d_in[6];
    const float* wout = (const float*)d_in[7];
    const float* bout = (const float*)d_in[8];

    char* ws = (char*)d_ws;
    unsigned short* buf0  = (unsigned short*)ws;                    // 64MB: x16, later o16
    unsigned short* qkv   = (unsigned short*)(ws + (64ll << 20));   // 192MB
    unsigned short* win16 = (unsigned short*)(ws + (256ll << 20));  // 6MB
    unsigned short* wqkT  = (unsigned short*)(ws + (262ll << 20));  // 2MB
    unsigned short* wvT   = (unsigned short*)(ws + (264ll << 20));  // 2MB
    unsigned short* wbig  = (unsigned short*)(ws + (266ll << 20));  // 6MB  [Wq';Wk';Wv'] bf16
    unsigned short* wo16  = (unsigned short*)(ws + (272ll << 20));  // 2MB
    float*          bbig  = (float*)(ws + (274ll << 20));           // 12KB combined bias
    unsigned short* o16   = buf0;

    dim3 blk(256);
    // dtype prep
    cvt_bf16<<<32768, 256, 0, stream>>>(x, buf0, 8388608);
    cvt_bf16<<<3072, 256, 0, stream>>>(win, win16, 786432);
    cvt_bf16<<<1024, 256, 0, stream>>>(wout, wo16, 262144);
    transpose_cvt<<<dim3(16, 16), blk, 0, stream>>>(wqk, wqkT, 1024);
    transpose_cvt<<<dim3(16, 16), blk, 0, stream>>>(wv, wvT, 1024);
    bias_prep<<<768, blk, 0, stream>>>(win, bqk, bv, bin, bbig);

    // weight fusion: Wq'[n,k] = sum_t Wq[n,t] Wqk[t,k]  ->  A=win16 rows, B=Wqk^T
    gemm_bt<false><<<dim3(8, 16), blk, 0, stream>>>(win16, 1024, wqkT, nullptr,
                                                    wbig, 1024, 1024);
    gemm_bt<false><<<dim3(8, 8), blk, 0, stream>>>(win16 + 2048ll * 1024, 1024, wvT, nullptr,
                                                   wbig + 2048ll * 1024, 1024, 1024);

    // fused projection: qkv[M,3072] = x16 @ W'^T + b'
    gemm_bt<false><<<dim3(24, 256), blk, 0, stream>>>(buf0, 1024, wbig, bbig, qkv, 3072, 1024);

    // attention within 4-token groups (writes o16 = buf0; x16 dead by now)
    attn4<<<16384, blk, 0, stream>>>(qkv, o16);

    // out[M,1024] fp32 = o @ Wo^T + bo
    gemm_bt<true><<<dim3(8, 256), blk, 0, stream>>>(o16, 1024, wo16, bout, d_out, 1024, 1024);
}

// Round 3
// 729.102 us; speedup vs baseline: 1.3372x; 1.0201x over previous
//
#include <hip/hip_runtime.h>
#include <hip/hip_bf16.h>

typedef __bf16 bf16x8 __attribute__((ext_vector_type(8)));
typedef float f32x4 __attribute__((ext_vector_type(4)));

__device__ __forceinline__ float bf2f(unsigned int u) {
    unsigned int x = u << 16;
    return __builtin_bit_cast(float, x);
}
__device__ __forceinline__ unsigned short f2bf(float f) {
    unsigned int x = __builtin_bit_cast(unsigned int, f);
    x += 0x7fffu + ((x >> 16) & 1u);   // RNE
    return (unsigned short)(x >> 16);
}

__device__ __forceinline__ void gld_lds16(const unsigned short* g, unsigned short* s) {
    __builtin_amdgcn_global_load_lds((const __attribute__((address_space(1))) void*)g,
                                     (__attribute__((address_space(3))) void*)s, 16, 0, 0);
}

// C[m,n] = sum_k A[m,k]*B[n,k] + bias[n].  A row stride = lda, B row stride = K.
// 128x128 tile, BK=32, 4 waves in 2x2, 16x16x32 bf16 MFMA (m97 structure).
// Operand-SWAPPED mfma: acc holds C^T fragments so each lane owns 4 consecutive
// output COLUMNS of one row -> packed uint2/float4 epilogue stores.
// Block rows with bm >= bsplit read B2 instead of B (merged weight-fusion GEMM).
template<bool OUT_F32>
__global__ __launch_bounds__(256) void gemm_bt(
    const unsigned short* __restrict__ A, int lda,
    const unsigned short* __restrict__ B,
    const unsigned short* __restrict__ B2, long bsplit,
    const float* __restrict__ bias,
    void* __restrict__ C, int N, int K)
{
    __shared__ unsigned short As[128 * 32];
    __shared__ unsigned short Bs[128 * 32];
    const int tid   = threadIdx.x;
    const int lane  = tid & 63;
    const int wave  = tid >> 6;
    const int wm    = (wave >> 1) * 64;
    const int wn    = (wave & 1) * 64;
    const int lrow  = lane & 15;
    const int lquad = lane >> 4;
    const long bm = (long)blockIdx.y * 128;
    const long bn = (long)blockIdx.x * 128;
    const unsigned short* Bp = (bm >= bsplit) ? B2 : B;

    f32x4 acc[4][4];
#pragma unroll
    for (int i = 0; i < 4; i++)
#pragma unroll
        for (int j = 0; j < 4; j++)
            acc[i][j] = (f32x4){0.f, 0.f, 0.f, 0.f};

    const int r0 = tid >> 2;
    const int c0 = (tid & 3) * 8;
    const unsigned short* Ag0 = A + (bm + r0) * (long)lda + c0;
    const unsigned short* Ag1 = A + (bm + r0 + 64) * (long)lda + c0;
    const unsigned short* Bg0 = Bp + (bn + r0) * (long)K + c0;
    const unsigned short* Bg1 = Bp + (bn + r0 + 64) * (long)K + c0;
    unsigned short* As0 = &As[tid * 8];
    unsigned short* As1 = &As[tid * 8 + 2048];
    unsigned short* Bs0 = &Bs[tid * 8];
    unsigned short* Bs1 = &Bs[tid * 8 + 2048];

    for (int k0 = 0; k0 < K; k0 += 32) {
        gld_lds16(Ag0 + k0, As0);
        gld_lds16(Ag1 + k0, As1);
        gld_lds16(Bg0 + k0, Bs0);
        gld_lds16(Bg1 + k0, Bs1);
        __syncthreads();
        bf16x8 af[4], bq[4];
#pragma unroll
        for (int i = 0; i < 4; i++)
            af[i] = *(const bf16x8*)&As[(wm + i * 16 + lrow) * 32 + lquad * 8];
#pragma unroll
        for (int j = 0; j < 4; j++)
            bq[j] = *(const bf16x8*)&Bs[(wn + j * 16 + lrow) * 32 + lquad * 8];
#pragma unroll
        for (int i = 0; i < 4; i++)
#pragma unroll
            for (int j = 0; j < 4; j++)
                acc[i][j] = __builtin_amdgcn_mfma_f32_16x16x32_bf16(bq[j], af[i], acc[i][j], 0, 0, 0);
        __syncthreads();
    }

    // Swapped C/D layout: M-row = lane&15 (+i*16), N-col = quad*4 + reg (+j*16).
#pragma unroll
    for (int i = 0; i < 4; i++) {
        const long row = bm + wm + i * 16 + lrow;
#pragma unroll
        for (int j = 0; j < 4; j++) {
            const int colb = (int)bn + wn + j * 16 + lquad * 4;
            float4 b4 = bias ? ((const float4*)bias)[colb >> 2]
                             : make_float4(0.f, 0.f, 0.f, 0.f);
            const float v0 = acc[i][j][0] + b4.x;
            const float v1 = acc[i][j][1] + b4.y;
            const float v2 = acc[i][j][2] + b4.z;
            const float v3 = acc[i][j][3] + b4.w;
            if (OUT_F32) {
                *(float4*)&((float*)C)[row * (long)N + colb] = make_float4(v0, v1, v2, v3);
            } else {
                unsigned int lo = (unsigned int)f2bf(v0) | ((unsigned int)f2bf(v1) << 16);
                unsigned int hi = (unsigned int)f2bf(v2) | ((unsigned int)f2bf(v3) << 16);
                *(uint2*)&((unsigned short*)C)[row * (long)N + colb] = make_uint2(lo, hi);
            }
        }
    }
}

// Per (group,head): 4x4 scores over hd=128, diag masked, softmax, o = A@v.
// 2 (g,h) pairs per wave: lanes 0-31 -> pair0, 32-63 -> pair1; 4 dims/lane;
// butterflies (masks 1..16) stay within each 32-lane half.
__global__ __launch_bounds__(256) void attn4(
    const unsigned short* __restrict__ QKV,  // [M][3072]: q|k|v
    unsigned short* __restrict__ O)          // [M][1024]
{
    const int wave = threadIdx.x >> 6;
    const int lane = threadIdx.x & 63;
    const int half = lane >> 5;
    const int l    = lane & 31;
    const int gh = blockIdx.x * 8 + wave * 2 + half;  // 0..65535
    const int g = gh >> 3, h = gh & 7;
    const long row0 = (long)g * 4;
    const int d0 = h * 128 + l * 4;
    const float scale = 0.08838834764831845f;  // 1/sqrt(128)

    float q[4][4], k[4][4], v[4][4];
#pragma unroll
    for (int i = 0; i < 4; i++) {
        const unsigned short* base = QKV + (row0 + i) * 3072 + d0;
        uint2 uq = *(const uint2*)base;
        uint2 uk = *(const uint2*)(base + 1024);
        uint2 uv = *(const uint2*)(base + 2048);
        q[i][0] = bf2f(uq.x & 0xffffu); q[i][1] = bf2f(uq.x >> 16);
        q[i][2] = bf2f(uq.y & 0xffffu); q[i][3] = bf2f(uq.y >> 16);
        k[i][0] = bf2f(uk.x & 0xffffu); k[i][1] = bf2f(uk.x >> 16);
        k[i][2] = bf2f(uk.y & 0xffffu); k[i][3] = bf2f(uk.y >> 16);
        v[i][0] = bf2f(uv.x & 0xffffu); v[i][1] = bf2f(uv.x >> 16);
        v[i][2] = bf2f(uv.y & 0xffffu); v[i][3] = bf2f(uv.y >> 16);
    }
    float s[4][4];
#pragma unroll
    for (int i = 0; i < 4; i++)
#pragma unroll
        for (int j = 0; j < 4; j++)
            s[i][j] = q[i][0] * k[j][0] + q[i][1] * k[j][1]
                    + q[i][2] * k[j][2] + q[i][3] * k[j][3];
#pragma unroll
    for (int m = 1; m < 32; m <<= 1)
#pragma unroll
        for (int i = 0; i < 4; i++)
#pragma unroll
            for (int j = 0; j < 4; j++)
                s[i][j] += __shfl_xor(s[i][j], m, 64);

#pragma unroll
    for (int i = 0; i < 4; i++) {
        float mx = -3.0e38f;
#pragma unroll
        for (int j = 0; j < 4; j++)
            if (j != i) mx = fmaxf(mx, s[i][j] * scale);
        float p[4], den = 0.f;
#pragma unroll
        for (int j = 0; j < 4; j++) {
            p[j] = (j == i) ? 0.f : __expf(s[i][j] * scale - mx);
            den += p[j];
        }
        const float inv = 1.f / den;
        float o0 = 0.f, o1 = 0.f, o2 = 0.f, o3 = 0.f;
#pragma unroll
        for (int j = 0; j < 4; j++) {
            const float a = p[j] * inv;
            o0 += a * v[j][0]; o1 += a * v[j][1];
            o2 += a * v[j][2]; o3 += a * v[j][3];
        }
        unsigned int lo = (unsigned int)f2bf(o0) | ((unsigned int)f2bf(o1) << 16);
        unsigned int hi = (unsigned int)f2bf(o2) | ((unsigned int)f2bf(o3) << 16);
        *(uint2*)(O + (row0 + i) * 1024 + d0) = make_uint2(lo, hi);
    }
}

__global__ __launch_bounds__(256) void cvt_bf16(const float* __restrict__ in,
                                                unsigned short* __restrict__ out, int n4)
{
    int i = blockIdx.x * blockDim.x + threadIdx.x;
    if (i >= n4) return;
    float4 v = ((const float4*)in)[i];
    unsigned int a = (unsigned int)f2bf(v.x) | ((unsigned int)f2bf(v.y) << 16);
    unsigned int b = (unsigned int)f2bf(v.z) | ((unsigned int)f2bf(v.w) << 16);
    ((uint2*)out)[i] = make_uint2(a, b);
}

// win (786432 float4s) and wout (262144 float4s) in one dispatch.
__global__ __launch_bounds__(256) void cvt_weights(const float* __restrict__ win,
                                                   unsigned short* __restrict__ win16,
                                                   const float* __restrict__ wout,
                                                   unsigned short* __restrict__ wo16)
{
    int i = blockIdx.x * blockDim.x + threadIdx.x;
    const float* in;
    unsigned short* out;
    int j;
    if (i < 786432) { in = win; out = win16; j = i; }
    else            { in = wout; out = wo16; j = i - 786432; }
    float4 v = ((const float4*)in)[j];
    unsigned int a = (unsigned int)f2bf(v.x) | ((unsigned int)f2bf(v.y) << 16);
    unsigned int b = (unsigned int)f2bf(v.z) | ((unsigned int)f2bf(v.w) << 16);
    ((uint2*)out)[j] = make_uint2(a, b);
}

// out[j][i] = bf16(in[i][j]) for n x n fp32; z selects (a->oa) or (b->ob).
__global__ __launch_bounds__(256) void transpose_cvt2(const float* __restrict__ a,
                                                      unsigned short* __restrict__ oa,
                                                      const float* __restrict__ b,
                                                      unsigned short* __restrict__ ob, int n)
{
    const float* in = blockIdx.z ? b : a;
    unsigned short* out = blockIdx.z ? ob : oa;
    __shared__ unsigned short tile[64][65];
    const int bx = blockIdx.x * 64, by = blockIdx.y * 64;
    const int tx = threadIdx.x & 63, ty = threadIdx.x >> 6;
    for (int r = ty; r < 64; r += 4)
        tile[r][tx] = f2bf(in[(long)(by + r) * n + bx + tx]);
    __syncthreads();
    for (int r = ty; r < 64; r += 4)
        out[(long)(bx + r) * n + by + tx] = tile[tx][r];
}

// bbig[row] = dot(win[row,:], row<2048 ? bqk : bv) + bin[row]; fp32 exact path.
__global__ __launch_bounds__(256) void bias_prep(const float* __restrict__ win,
                                                 const float* __restrict__ bqk,
                                                 const float* __restrict__ bv,
                                                 const float* __restrict__ bin,
                                                 float* __restrict__ bbig)
{
    const int row = blockIdx.x * 4 + (threadIdx.x >> 6);
    const int lane = threadIdx.x & 63;
    const float* b = (row < 2048) ? bqk : bv;
    float s = 0.f;
    for (int t = lane; t < 1024; t += 64) s += win[(long)row * 1024 + t] * b[t];
#pragma unroll
    for (int m = 1; m < 64; m <<= 1) s += __shfl_xor(s, m, 64);
    if (lane == 0) bbig[row] = s + bin[row];
}

extern "C" void kernel_launch(void* const* d_in, const int* in_sizes, int n_in,
                              void* d_out, int out_size, void* d_ws, size_t ws_size,
                              hipStream_t stream)
{
    (void)in_sizes; (void)n_in; (void)out_size; (void)ws_size;
    const float* x    = (const float*)d_in[0];
    const float* wqk  = (const float*)d_in[1];
    const float* bqk  = (const float*)d_in[2];
    const float* wv   = (const float*)d_in[3];
    const float* bv   = (const float*)d_in[4];
    const float* win  = (const float*)d_in[5];
    const float* bin  = (const float*)d_in[6];
    const float* wout = (const float*)d_in[7];
    const float* bout = (const float*)d_in[8];

    char* ws = (char*)d_ws;
    unsigned short* buf0  = (unsigned short*)ws;                    // 64MB: x16, later o16
    unsigned short* qkv   = (unsigned short*)(ws + (64ll << 20));   // 192MB
    unsigned short* win16 = (unsigned short*)(ws + (256ll << 20));  // 6MB
    unsigned short* wqkT  = (unsigned short*)(ws + (262ll << 20));  // 2MB
    unsigned short* wvT   = (unsigned short*)(ws + (264ll << 20));  // 2MB
    unsigned short* wbig  = (unsigned short*)(ws + (266ll << 20));  // 6MB  [Wq';Wk';Wv'] bf16
    unsigned short* wo16  = (unsigned short*)(ws + (272ll << 20));  // 2MB
    float*          bbig  = (float*)(ws + (274ll << 20));           // 12KB combined bias
    unsigned short* o16   = buf0;
    const long NOSPLIT = 1ll << 40;

    dim3 blk(256);
    // dtype prep
    cvt_bf16<<<32768, 256, 0, stream>>>(x, buf0, 8388608);
    cvt_weights<<<4096, 256, 0, stream>>>(win, win16, wout, wo16);
    transpose_cvt2<<<dim3(16, 16, 2), blk, 0, stream>>>(wqk, wqkT, wv, wvT, 1024);
    bias_prep<<<768, blk, 0, stream>>>(win, bqk, bv, bin, bbig);

    // merged weight fusion: wbig[3072,1024]; rows<2048 use Wqk^T, rows>=2048 use Wv^T
    gemm_bt<false><<<dim3(8, 24), blk, 0, stream>>>(win16, 1024, wqkT, wvT, 2048,
                                                    nullptr, wbig, 1024, 1024);

    // fused projection: qkv[M,3072] = x16 @ W'^T + b'
    gemm_bt<false><<<dim3(24, 256), blk, 0, stream>>>(buf0, 1024, wbig, wbig, NOSPLIT,
                                                      bbig, qkv, 3072, 1024);

    // attention within 4-token groups (writes o16 = buf0; x16 dead by now)
    attn4<<<8192, blk, 0, stream>>>(qkv, o16);

    // out[M,1024] fp32 = o @ Wo^T + bo
    gemm_bt<true><<<dim3(8, 256), blk, 0, stream>>>(o16, 1024, wo16, wo16, NOSPLIT,
                                                    bout, d_out, 1024, 1024);
}